// Round 2
// baseline (156.470 us; speedup 1.0000x reference)
//
#include <hip/hip_runtime.h>

// pred/target (4,4,64,128,128) fp32 -> 16 volumes of 64x128x128.
#define NB 16
#define DD 64
#define HH 128
#define WW 128
#define HW (HH * WW)

constexpr int TH = 8;                  // output rows per block
constexpr int LY = TH + 2;             // 10 input rows
constexpr int PL = LY * WW;            // LDS plane-slot stride (floats) = 1280
constexpr int RING = 6;                // plane ring slots -> 30720 B LDS
constexpr int NT = 8;                  // tiles per quarter (2 output planes each)
constexpr int NQ = 4;                  // d-quarters per volume (4*16 = 64 planes)
constexpr int SLOTS = 3;               // 640 float4 positions / 256 threads (last half-populated)
constexpr float INV_COUNT = 1.0f / 50331648.0f; // 1/(3*16*64*128*128)

__global__ void zero_out_kernel(float* out) {
    if (threadIdx.x == 0 && blockIdx.x == 0) out[0] = 0.0f;
}

__global__ __launch_bounds__(256, 4) void sobel_l1_kernel(
    const float* __restrict__ pred,
    const float* __restrict__ target,
    float* __restrict__ out)
{
    // 6-slot plane ring: each input plane is staged to LDS exactly once per
    // quarter (d-amplification 18/16 vs 2.0x for the old 4-plane tiles).
    // Slot for relative plane p is (p+1) % 6; tile tau computes planes
    // 2t-1..2t+2 (slots (2t..2t+3)%6) while prefetching planes 2t+3, 2t+4
    // into slots (2t+4..2t+5)%6 -- always disjoint, so one barrier per tile.
    __shared__ float ring[RING * PL];  // 30720 B -> LDS allows 5 blocks/CU

    const int tid = threadIdx.x;
    int b = blockIdx.x;                // 1024 blocks: 16 bh x 4 quarter x 16 bn
    const int bh = b & 15; b >>= 4;
    const int q  = b & 3;  b >>= 2;
    const int bn = b;

    const int h0 = bh * TH;
    const int dbase = q * (NT * 2);                // 0, 16, 32, 48
    const size_t nbase = (size_t)bn * (size_t)(DD * HW);

    // ---- per-slot constants: 640 (plane-pair) float4 positions over 256 threads ----
    // position i: z = i/320 (which of the 2 new planes), y = (i%320)/32 (row 0..9),
    // q4 = i%32 (w-quad). Slot k=2 is live only for tid < 128.
    const bool k2ok = tid < 128;
    int  soff[SLOTS];   // clamped-row load offset within plane
    int  stoff[SLOTS];  // unclamped LDS store offset within plane slot
    int  sz[SLOTS];     // which new plane (0/1)
    bool sokh[SLOTS];   // row in range
#pragma unroll
    for (int k = 0; k < SLOTS; ++k) {
        const int i  = (k < 2) ? (k * 256 + tid) : (512 + (tid & 127));
        const int z  = i / 320;
        const int r  = i - z * 320;
        const int y  = r >> 5;
        const int q4 = r & 31;
        const int gh = h0 - 1 + y;
        sokh[k]  = (unsigned)gh < HH;
        soff[k]  = min(max(gh, 0), HH - 1) * WW + 4 * q4;
        stoff[k] = y * WW + 4 * q4;
        sz[k]    = z;
    }

    float4 sp[SLOTS], sq[SLOTS];       // raw staging (subtract deferred to store)

    // p0 = relative index of first new plane (p0 and p0+1 are loaded)
    auto load_pair = [&](int p0) {
#pragma unroll
        for (int k = 0; k < SLOTS; ++k) {
            if (k < 2 || k2ok) {
                const int gd  = dbase + p0 + sz[k];
                const int gdc = min(max(gd, 0), DD - 1);
                const size_t idx = nbase + (size_t)gdc * HW + soff[k];
                sp[k] = *(const float4*)(pred + idx);
                sq[k] = *(const float4*)(target + idx);
            }
        }
    };

    auto store_pair = [&](int p0) {
        const int base0 = ((p0 + 1) % RING) * PL;
        const int base1 = ((p0 + 2) % RING) * PL;
#pragma unroll
        for (int k = 0; k < SLOTS; ++k) {
            if (k < 2 || k2ok) {
                const int gd = dbase + p0 + sz[k];
                const float m = (sokh[k] && (unsigned)gd < DD) ? 1.0f : 0.0f;
                float* dst = &ring[(sz[k] ? base1 : base0) + stoff[k]];
                *(float4*)dst = float4{(sp[k].x - sq[k].x) * m,
                                       (sp[k].y - sq[k].y) * m,
                                       (sp[k].z - sq[k].z) * m,
                                       (sp[k].w - sq[k].w) * m};
            }
        }
    };

    const int tc = tid & 31;           // w-quad
    const int lh = tid >> 5;           // output row in tile

    auto compute_tile = [&](int tau, float& acc) {
        // Per-plane partials: A = s(h)s(w)v, Bh = d(h)s(w)v, Bw = s(h)d(w)v.
        auto plane_l = [&](int base, float4& A_, float4& Bh_, float4& Bw_) {
            float4 rs[3], rdw[3];
#pragma unroll
            for (int r = 0; r < 3; ++r) {
                const float4 v = *(const float4*)&ring[base + (lh + r) * WW + 4 * tc];
                float lm = __shfl_up(v.w, 1, 32);
                float rp = __shfl_down(v.x, 1, 32);
                if (tc == 0)  lm = 0.f;
                if (tc == 31) rp = 0.f;
                rs[r]  = float4{lm  + 2.f * v.x + v.y,
                                v.x + 2.f * v.y + v.z,
                                v.y + 2.f * v.z + v.w,
                                v.z + 2.f * v.w + rp};
                rdw[r] = float4{v.y - lm, v.z - v.x, v.w - v.y, rp - v.z};
            }
            A_  = float4{rs[0].x + 2.f * rs[1].x + rs[2].x,
                         rs[0].y + 2.f * rs[1].y + rs[2].y,
                         rs[0].z + 2.f * rs[1].z + rs[2].z,
                         rs[0].w + 2.f * rs[1].w + rs[2].w};
            Bh_ = float4{rs[2].x - rs[0].x, rs[2].y - rs[0].y,
                         rs[2].z - rs[0].z, rs[2].w - rs[0].w};
            Bw_ = float4{rdw[0].x + 2.f * rdw[1].x + rdw[2].x,
                         rdw[0].y + 2.f * rdw[1].y + rdw[2].y,
                         rdw[0].z + 2.f * rdw[1].z + rdw[2].z,
                         rdw[0].w + 2.f * rdw[1].w + rdw[2].w};
        };

        // slot bases for the 4 planes 2*tau-1 .. 2*tau+2
        int sb[4];
#pragma unroll
        for (int j = 0; j < 4; ++j) sb[j] = ((2 * tau + j) % RING) * PL;

        float4 rA[3], rBh[3], rBw[3];
        plane_l(sb[0], rA[0], rBh[0], rBw[0]);
        plane_l(sb[1], rA[1], rBh[1], rBw[1]);
#pragma unroll
        for (int ld = 0; ld < 2; ++ld) {
            const int s0 = ld % 3, s1 = (ld + 1) % 3, s2 = (ld + 2) % 3;
            plane_l(sb[ld + 2], rA[s2], rBh[s2], rBw[s2]);
            const float4 a0 = rA[s0],  a2 = rA[s2];
            const float4 b0 = rBh[s0], b1 = rBh[s1], b2 = rBh[s2];
            const float4 c0 = rBw[s0], c1 = rBw[s1], c2 = rBw[s2];
            acc += fabsf(a2.x - a0.x) + fabsf(a2.y - a0.y)
                 + fabsf(a2.z - a0.z) + fabsf(a2.w - a0.w);
            acc += fabsf(b0.x + 2.f * b1.x + b2.x) + fabsf(b0.y + 2.f * b1.y + b2.y)
                 + fabsf(b0.z + 2.f * b1.z + b2.z) + fabsf(b0.w + 2.f * b1.w + b2.w);
            acc += fabsf(c0.x + 2.f * c1.x + c2.x) + fabsf(c0.y + 2.f * c1.y + c2.y)
                 + fabsf(c0.z + 2.f * c1.z + c2.z) + fabsf(c0.w + 2.f * c1.w + c2.w);
        }
    };

    // ---- prologue: stage planes -1,0,1,2 into slots 0..3 ----
    load_pair(-1); store_pair(-1);
    load_pair(1);  store_pair(1);
    __syncthreads();

    // ---- main loop: compute planes 2t-1..2t+2, prefetch planes 2t+3,2t+4 ----
    float acc = 0.0f;
    for (int tau = 0; tau < NT; ++tau) {
        if (tau + 1 < NT) load_pair(2 * tau + 3);   // in flight during compute
        compute_tile(tau, acc);
        if (tau + 1 < NT) store_pair(2 * tau + 3);
        __syncthreads();   // publishes prefetched planes; orders ring reuse
    }

    // ---- block reduction (reuse ring[0..3] as wave-sum scratch) ----
#pragma unroll
    for (int off = 32; off > 0; off >>= 1)
        acc += __shfl_down(acc, off, 64);
    if ((tid & 63) == 0) ring[tid >> 6] = acc;
    __syncthreads();
    if (tid == 0) {
        const float s = ring[0] + ring[1] + ring[2] + ring[3];
        atomicAdd(out, s * INV_COUNT);
    }
}

extern "C" void kernel_launch(void* const* d_in, const int* in_sizes, int n_in,
                              void* d_out, int out_size, void* d_ws, size_t ws_size,
                              hipStream_t stream) {
    const float* pred   = (const float*)d_in[0];
    const float* target = (const float*)d_in[1];
    float* out = (float*)d_out;

    zero_out_kernel<<<1, 64, 0, stream>>>(out);

    // 16 volumes * 4 d-quarters * 16 h-tiles = 1024 blocks (4 blocks/CU)
    const int nblocks = NB * NQ * (HH / TH);
    sobel_l1_kernel<<<nblocks, 256, 0, stream>>>(pred, target, out);
}